// Round 1
// baseline (276.232 us; speedup 1.0000x reference)
//
#include <hip/hip_runtime.h>
#include <hip/hip_bf16.h>
#include <math.h>

#define N_NODES 2048
#define IN_F    1024
#define NH      8
#define HF      32
#define OUTF    256   // NH*HF

// ---------------- Kernel 1: g = h @ W  (2048x1024 @ 1024x256, fp32) --------
#define TM 64
#define TN 32
#define TK 32

__global__ __launch_bounds__(256)
void gemm_g_kernel(const float* __restrict__ A, const float* __restrict__ B,
                   float* __restrict__ C) {
  __shared__ float As[TK][TM + 1];   // [k][m], pad -> stride 65 (conflict-free)
  __shared__ float Bs[TK][TN + 1];   // [k][n], stride 33
  const int m0 = blockIdx.x * TM;
  const int c0 = blockIdx.y * TN;
  const int tid = threadIdx.x;
  const int tx = tid & 15;   // col group: cols tx*2..tx*2+1
  const int ty = tid >> 4;   // row group: rows ty*4..ty*4+3
  float acc[4][2] = {{0.f,0.f},{0.f,0.f},{0.f,0.f},{0.f,0.f}};

  for (int k0 = 0; k0 < IN_F; k0 += TK) {
    {
      const int kk = tid & 31, m = tid >> 5;
      #pragma unroll
      for (int r = 0; r < 8; ++r)
        As[kk][m + r * 8] = A[(m0 + m + r * 8) * IN_F + k0 + kk];
    }
    {
      const int c = tid & 31, kk = tid >> 5;
      #pragma unroll
      for (int r = 0; r < 4; ++r)
        Bs[kk + r * 8][c] = B[(k0 + kk + r * 8) * OUTF + c0 + c];
    }
    __syncthreads();
    #pragma unroll
    for (int kk = 0; kk < TK; ++kk) {
      const float a0 = As[kk][ty * 4 + 0];
      const float a1 = As[kk][ty * 4 + 1];
      const float a2 = As[kk][ty * 4 + 2];
      const float a3 = As[kk][ty * 4 + 3];
      const float b0 = Bs[kk][tx * 2 + 0];
      const float b1 = Bs[kk][tx * 2 + 1];
      acc[0][0] = fmaf(a0, b0, acc[0][0]); acc[0][1] = fmaf(a0, b1, acc[0][1]);
      acc[1][0] = fmaf(a1, b0, acc[1][0]); acc[1][1] = fmaf(a1, b1, acc[1][1]);
      acc[2][0] = fmaf(a2, b0, acc[2][0]); acc[2][1] = fmaf(a2, b1, acc[2][1]);
      acc[3][0] = fmaf(a3, b0, acc[3][0]); acc[3][1] = fmaf(a3, b1, acc[3][1]);
    }
    __syncthreads();
  }
  #pragma unroll
  for (int r = 0; r < 4; ++r) {
    const int row = m0 + ty * 4 + r;
    #pragma unroll
    for (int c = 0; c < 2; ++c)
      C[row * OUTF + c0 + tx * 2 + c] = acc[r][c];
  }
}

// ---------------- Kernel 2: s_l[i,h] = g[i,h,:]·a_l ; s_r likewise ---------
__global__ __launch_bounds__(256)
void score_kernel(const float* __restrict__ g, const float* __restrict__ a,
                  float* __restrict__ s_l, float* __restrict__ s_r) {
  const int idx = blockIdx.x * 256 + threadIdx.x;  // idx = i*8 + h
  if (idx >= N_NODES * NH) return;
  const float* gr = g + idx * HF;
  float sl = 0.f, sr = 0.f;
  #pragma unroll
  for (int f = 0; f < HF; f += 4) {
    const float4 gv = *(const float4*)(gr + f);
    const float4 al = *(const float4*)(a + f);
    const float4 ar = *(const float4*)(a + HF + f);
    sl = fmaf(gv.x, al.x, sl); sl = fmaf(gv.y, al.y, sl);
    sl = fmaf(gv.z, al.z, sl); sl = fmaf(gv.w, al.w, sl);
    sr = fmaf(gv.x, ar.x, sr); sr = fmaf(gv.y, ar.y, sr);
    sr = fmaf(gv.z, ar.z, sr); sr = fmaf(gv.w, ar.w, sr);
  }
  s_l[idx] = sl;
  s_r[idx] = sr;
}

// ---------------- Kernel 3: fused masked softmax + PV ----------------------
// Block: 8 nodes (i0..i0+7), 512 threads. Two stat sweeps + chunked att/PV.
#define ISTRIDE 520   // 8*65: att[i][h*64+j], i-stride padded for banks

__global__ __launch_bounds__(512)
void attn_kernel(const int* __restrict__ adj, const float* __restrict__ g,
                 const float* __restrict__ s_l, const float* __restrict__ s_r,
                 float* __restrict__ out) {
  const int i0 = blockIdx.x * 8;
  const int tid = threadIdx.x;
  __shared__ float sl_s[8][8];
  __shared__ float m_s[8][8];
  __shared__ float li_s[8][8];
  __shared__ float att[8 * ISTRIDE];

  if (tid < 64) sl_s[tid >> 3][tid & 7] = s_l[(i0 + (tid >> 3)) * NH + (tid & 7)];
  __syncthreads();

  // ---- Pass A: per-(i,h) max and sum-of-exp over j. One wave per node i.
  const int i = tid >> 6;
  const int t = tid & 63;
  const int arow = (i0 + i) * N_NODES;

  float slh[8];
  #pragma unroll
  for (int hh = 0; hh < 8; ++hh) slh[hh] = sl_s[i][hh];

  float mreg[8];
  #pragma unroll
  for (int hh = 0; hh < 8; ++hh) mreg[hh] = -1e30f;

  for (int j = t; j < N_NODES; j += 64) {
    const int ad = adj[arow + j];
    const float4 sr0 = *(const float4*)(s_r + j * NH);
    const float4 sr1 = *(const float4*)(s_r + j * NH + 4);
    const float srv[8] = {sr0.x, sr0.y, sr0.z, sr0.w, sr1.x, sr1.y, sr1.z, sr1.w};
    #pragma unroll
    for (int hh = 0; hh < 8; ++hh) {
      float e = slh[hh] + srv[hh];
      e = fmaxf(e, 0.2f * e);          // leaky relu
      e = ad ? e : -1e30f;             // mask
      mreg[hh] = fmaxf(mreg[hh], e);
    }
  }
  #pragma unroll
  for (int off = 32; off >= 1; off >>= 1) {
    #pragma unroll
    for (int hh = 0; hh < 8; ++hh)
      mreg[hh] = fmaxf(mreg[hh], __shfl_xor(mreg[hh], off, 64));
  }
  if (t == 0) {
    #pragma unroll
    for (int hh = 0; hh < 8; ++hh) m_s[i][hh] = mreg[hh];
  }

  float lreg[8] = {0.f,0.f,0.f,0.f,0.f,0.f,0.f,0.f};
  for (int j = t; j < N_NODES; j += 64) {
    const int ad = adj[arow + j];
    const float4 sr0 = *(const float4*)(s_r + j * NH);
    const float4 sr1 = *(const float4*)(s_r + j * NH + 4);
    const float srv[8] = {sr0.x, sr0.y, sr0.z, sr0.w, sr1.x, sr1.y, sr1.z, sr1.w};
    #pragma unroll
    for (int hh = 0; hh < 8; ++hh) {
      float e = slh[hh] + srv[hh];
      e = fmaxf(e, 0.2f * e);
      e = ad ? e : -1e30f;             // exp(-1e30 - m) flushes to 0
      lreg[hh] += __expf(e - mreg[hh]);
    }
  }
  #pragma unroll
  for (int off = 32; off >= 1; off >>= 1) {
    #pragma unroll
    for (int hh = 0; hh < 8; ++hh)
      lreg[hh] += __shfl_xor(lreg[hh], off, 64);
  }
  if (t == 0) {
    #pragma unroll
    for (int hh = 0; hh < 8; ++hh) li_s[i][hh] = 1.0f / lreg[hh];
  }
  __syncthreads();

  // ---- Pass B: chunked att staging + PV accumulate.
  // stage role: (h_st = tid>>6, j_st = tid&63), computes att for all 8 i's
  const int h_st = tid >> 6;
  const int j_st = tid & 63;
  float slc[8], mc[8], lc[8];
  #pragma unroll
  for (int k = 0; k < 8; ++k) {
    slc[k] = sl_s[k][h_st];
    mc[k]  = m_s[k][h_st];
    lc[k]  = li_s[k][h_st];
  }
  // PV role: (hB = tid>>6, fq = (tid>>3)&7, ii = tid&7) -> 4 f's, 1 i
  const int hB = tid >> 6;
  const int fq = (tid >> 3) & 7;
  const int ii = tid & 7;
  float4 acc = {0.f, 0.f, 0.f, 0.f};
  const float* ab = att + ii * ISTRIDE + hB * 64;

  for (int jc = 0; jc < N_NODES; jc += 64) {
    // stage att[i][h][j] for this 64-j chunk
    const float srh = s_r[(jc + j_st) * NH + h_st];
    #pragma unroll
    for (int k = 0; k < 8; ++k) {
      const int ad = adj[(i0 + k) * N_NODES + jc + j_st];
      float e = slc[k] + srh;
      e = fmaxf(e, 0.2f * e);
      const float p = ad ? __expf(e - mc[k]) * lc[k] : 0.f;
      att[k * ISTRIDE + h_st * 64 + j_st] = p;
    }
    __syncthreads();
    // PV: acc[f] += att[ii][hB][j] * g[jc+j][hB][f]
    const float* gb = g + jc * OUTF + hB * HF + fq * 4;
    #pragma unroll 4
    for (int j4 = 0; j4 < 64; j4 += 4) {
      const float4 av = *(const float4*)(ab + j4);
      const float4 g0 = *(const float4*)(gb + (j4 + 0) * OUTF);
      const float4 g1 = *(const float4*)(gb + (j4 + 1) * OUTF);
      const float4 g2 = *(const float4*)(gb + (j4 + 2) * OUTF);
      const float4 g3 = *(const float4*)(gb + (j4 + 3) * OUTF);
      acc.x = fmaf(av.x, g0.x, acc.x); acc.x = fmaf(av.y, g1.x, acc.x);
      acc.x = fmaf(av.z, g2.x, acc.x); acc.x = fmaf(av.w, g3.x, acc.x);
      acc.y = fmaf(av.x, g0.y, acc.y); acc.y = fmaf(av.y, g1.y, acc.y);
      acc.y = fmaf(av.z, g2.y, acc.y); acc.y = fmaf(av.w, g3.y, acc.y);
      acc.z = fmaf(av.x, g0.z, acc.z); acc.z = fmaf(av.y, g1.z, acc.z);
      acc.z = fmaf(av.z, g2.z, acc.z); acc.z = fmaf(av.w, g3.z, acc.z);
      acc.w = fmaf(av.x, g0.w, acc.w); acc.w = fmaf(av.y, g1.w, acc.w);
      acc.w = fmaf(av.z, g2.w, acc.w); acc.w = fmaf(av.w, g3.w, acc.w);
    }
    __syncthreads();
  }

  float* op = out + (i0 + ii) * OUTF + hB * HF + fq * 4;
  *(float4*)op = acc;
}

// ---------------------------------------------------------------------------
extern "C" void kernel_launch(void* const* d_in, const int* in_sizes, int n_in,
                              void* d_out, int out_size, void* d_ws, size_t ws_size,
                              hipStream_t stream) {
  const float* h   = (const float*)d_in[0];
  const int*   adj = (const int*)d_in[1];
  const float* W   = (const float*)d_in[2];
  const float* a   = (const float*)d_in[3];
  float* out = (float*)d_out;

  float* g   = (float*)d_ws;                 // 2048*256 floats
  float* s_l = g + N_NODES * OUTF;           // 2048*8
  float* s_r = s_l + N_NODES * NH;           // 2048*8

  gemm_g_kernel<<<dim3(N_NODES / TM, OUTF / TN), 256, 0, stream>>>(h, W, g);
  score_kernel<<<(N_NODES * NH) / 256, 256, 0, stream>>>(g, a, s_l, s_r);
  attn_kernel<<<N_NODES / 8, 512, 0, stream>>>(adj, g, s_l, s_r, out);
}

// Round 2
// 186.445 us; speedup vs baseline: 1.4816x; 1.4816x over previous
//
#include <hip/hip_runtime.h>
#include <hip/hip_bf16.h>
#include <math.h>

#define N_NODES 2048
#define IN_F    1024
#define NH      8
#define HF      32
#define OUTF    256   // NH*HF
#define JSPLIT  4
#define JR      (N_NODES / JSPLIT)   // 512 j's per partial block

// ---------------- Kernel 1: g = h @ W  (2048x1024 @ 1024x256, fp32) --------
#define TM 64
#define TN 32
#define TK 32

__global__ __launch_bounds__(256)
void gemm_g_kernel(const float* __restrict__ A, const float* __restrict__ B,
                   float* __restrict__ C) {
  __shared__ float As[TK][TM + 1];
  __shared__ float Bs[TK][TN + 1];
  const int m0 = blockIdx.x * TM;
  const int c0 = blockIdx.y * TN;
  const int tid = threadIdx.x;
  const int tx = tid & 15;
  const int ty = tid >> 4;
  float acc[4][2] = {{0.f,0.f},{0.f,0.f},{0.f,0.f},{0.f,0.f}};

  for (int k0 = 0; k0 < IN_F; k0 += TK) {
    {
      const int kk = tid & 31, m = tid >> 5;
      #pragma unroll
      for (int r = 0; r < 8; ++r)
        As[kk][m + r * 8] = A[(m0 + m + r * 8) * IN_F + k0 + kk];
    }
    {
      const int c = tid & 31, kk = tid >> 5;
      #pragma unroll
      for (int r = 0; r < 4; ++r)
        Bs[kk + r * 8][c] = B[(k0 + kk + r * 8) * OUTF + c0 + c];
    }
    __syncthreads();
    #pragma unroll
    for (int kk = 0; kk < TK; ++kk) {
      const float a0 = As[kk][ty * 4 + 0];
      const float a1 = As[kk][ty * 4 + 1];
      const float a2 = As[kk][ty * 4 + 2];
      const float a3 = As[kk][ty * 4 + 3];
      const float b0 = Bs[kk][tx * 2 + 0];
      const float b1 = Bs[kk][tx * 2 + 1];
      acc[0][0] = fmaf(a0, b0, acc[0][0]); acc[0][1] = fmaf(a0, b1, acc[0][1]);
      acc[1][0] = fmaf(a1, b0, acc[1][0]); acc[1][1] = fmaf(a1, b1, acc[1][1]);
      acc[2][0] = fmaf(a2, b0, acc[2][0]); acc[2][1] = fmaf(a2, b1, acc[2][1]);
      acc[3][0] = fmaf(a3, b0, acc[3][0]); acc[3][1] = fmaf(a3, b1, acc[3][1]);
    }
    __syncthreads();
  }
  #pragma unroll
  for (int r = 0; r < 4; ++r) {
    const int row = m0 + ty * 4 + r;
    #pragma unroll
    for (int c = 0; c < 2; ++c)
      C[row * OUTF + c0 + tx * 2 + c] = acc[r][c];
  }
}

// ---------------- Kernel 2: s_l[i,h] and transposed s_r_t[h][j] ------------
__global__ __launch_bounds__(256)
void score_kernel(const float* __restrict__ g, const float* __restrict__ a,
                  float* __restrict__ s_l, float* __restrict__ s_r_t) {
  const int idx = blockIdx.x * 256 + threadIdx.x;  // idx = i*8 + h
  if (idx >= N_NODES * NH) return;
  const int i = idx >> 3, h = idx & 7;
  const float* gr = g + idx * HF;
  float sl = 0.f, sr = 0.f;
  #pragma unroll
  for (int f = 0; f < HF; f += 4) {
    const float4 gv = *(const float4*)(gr + f);
    const float4 al = *(const float4*)(a + f);
    const float4 ar = *(const float4*)(a + HF + f);
    sl = fmaf(gv.x, al.x, sl); sl = fmaf(gv.y, al.y, sl);
    sl = fmaf(gv.z, al.z, sl); sl = fmaf(gv.w, al.w, sl);
    sr = fmaf(gv.x, ar.x, sr); sr = fmaf(gv.y, ar.y, sr);
    sr = fmaf(gv.z, ar.z, sr); sr = fmaf(gv.w, ar.w, sr);
  }
  s_l[idx] = sl;
  s_r_t[h * N_NODES + i] = sr;
}

// ---------------- Kernel 3: partial masked-softmax PV (no max pass) --------
// Block: 8 nodes x 512 j's, 512 threads. Unnormalized: w = adj ? exp(e) : 0.
// Partial out = sum_j w*g ; partial denom = sum_j w. Divide in reduce kernel.
#define ISTRIDE 520   // 8*65: att[i][h*64+j], i-stride padded for banks

__global__ __launch_bounds__(512)
void pv_partial_kernel(const int* __restrict__ adj, const float* __restrict__ g,
                       const float* __restrict__ s_l, const float* __restrict__ s_r_t,
                       float* __restrict__ pout, float* __restrict__ pl) {
  const int i0 = blockIdx.x * 8;
  const int split = blockIdx.y;
  const int j0 = split * JR;
  const int tid = threadIdx.x;
  __shared__ float sl_s[8][8];
  __shared__ float att[8 * ISTRIDE];

  if (tid < 64) sl_s[tid >> 3][tid & 7] = s_l[(i0 + (tid >> 3)) * NH + (tid & 7)];
  __syncthreads();

  // stage role: wave h_st handles head h_st, lane j_st = j offset in chunk
  const int h_st = tid >> 6;
  const int j_st = tid & 63;
  float slc[8];
  #pragma unroll
  for (int k = 0; k < 8; ++k) slc[k] = sl_s[k][h_st];
  float lacc[8] = {0.f,0.f,0.f,0.f,0.f,0.f,0.f,0.f};

  // PV role: (hB, fq, ii) -> head, f-quad, node-in-group
  const int hB = tid >> 6;
  const int fq = (tid >> 3) & 7;
  const int ii = tid & 7;
  float4 acc = {0.f, 0.f, 0.f, 0.f};
  const float* ab = att + ii * ISTRIDE + hB * 64;

  for (int jc = j0; jc < j0 + JR; jc += 64) {
    // stage w[i][h][j] for this 64-j chunk, accumulate denom
    const float srh = s_r_t[h_st * N_NODES + jc + j_st];
    #pragma unroll
    for (int k = 0; k < 8; ++k) {
      const int ad = adj[(i0 + k) * N_NODES + jc + j_st];
      float e = slc[k] + srh;
      e = fmaxf(e, 0.2f * e);                 // leaky relu
      const float w = ad ? __expf(e) : 0.f;   // bounded: |e| <~ 12 -> safe
      att[k * ISTRIDE + h_st * 64 + j_st] = w;
      lacc[k] += w;
    }
    __syncthreads();
    // PV: acc[f] += w[ii][hB][j] * g[jc+j][hB][f]
    const float* gb = g + jc * OUTF + hB * HF + fq * 4;
    #pragma unroll 4
    for (int j4 = 0; j4 < 64; j4 += 4) {
      const float4 av = *(const float4*)(ab + j4);
      const float4 g0 = *(const float4*)(gb + (j4 + 0) * OUTF);
      const float4 g1 = *(const float4*)(gb + (j4 + 1) * OUTF);
      const float4 g2 = *(const float4*)(gb + (j4 + 2) * OUTF);
      const float4 g3 = *(const float4*)(gb + (j4 + 3) * OUTF);
      acc.x = fmaf(av.x, g0.x, acc.x); acc.x = fmaf(av.y, g1.x, acc.x);
      acc.x = fmaf(av.z, g2.x, acc.x); acc.x = fmaf(av.w, g3.x, acc.x);
      acc.y = fmaf(av.x, g0.y, acc.y); acc.y = fmaf(av.y, g1.y, acc.y);
      acc.y = fmaf(av.z, g2.y, acc.y); acc.y = fmaf(av.w, g3.y, acc.y);
      acc.z = fmaf(av.x, g0.z, acc.z); acc.z = fmaf(av.y, g1.z, acc.z);
      acc.z = fmaf(av.z, g2.z, acc.z); acc.z = fmaf(av.w, g3.z, acc.z);
      acc.w = fmaf(av.x, g0.w, acc.w); acc.w = fmaf(av.y, g1.w, acc.w);
      acc.w = fmaf(av.z, g2.w, acc.w); acc.w = fmaf(av.w, g3.w, acc.w);
    }
    __syncthreads();
  }

  // denom partials: reduce lacc over the 64 j-lanes of wave h_st
  #pragma unroll
  for (int off = 32; off >= 1; off >>= 1) {
    #pragma unroll
    for (int k = 0; k < 8; ++k)
      lacc[k] += __shfl_xor(lacc[k], off, 64);
  }
  if (j_st == 0) {
    #pragma unroll
    for (int k = 0; k < 8; ++k)
      pl[split * (N_NODES * NH) + (i0 + k) * NH + h_st] = lacc[k];
  }

  float* op = pout + split * (N_NODES * OUTF) + (i0 + ii) * OUTF + hB * HF + fq * 4;
  *(float4*)op = acc;
}

// ---------------- Kernel 4: sum partials, normalize ------------------------
__global__ __launch_bounds__(256)
void reduce_kernel(const float* __restrict__ pout, const float* __restrict__ pl,
                   float* __restrict__ out) {
  const int idx = blockIdx.x * 256 + threadIdx.x;  // over N_NODES*OUTF
  float s = 0.f;
  #pragma unroll
  for (int p = 0; p < JSPLIT; ++p) s += pout[p * (N_NODES * OUTF) + idx];
  const int ih = idx >> 5;  // i*8 + h
  float l = 0.f;
  #pragma unroll
  for (int p = 0; p < JSPLIT; ++p) l += pl[p * (N_NODES * NH) + ih];
  out[idx] = s / l;
}

// ---------------------------------------------------------------------------
extern "C" void kernel_launch(void* const* d_in, const int* in_sizes, int n_in,
                              void* d_out, int out_size, void* d_ws, size_t ws_size,
                              hipStream_t stream) {
  const float* h   = (const float*)d_in[0];
  const int*   adj = (const int*)d_in[1];
  const float* W   = (const float*)d_in[2];
  const float* a   = (const float*)d_in[3];
  float* out = (float*)d_out;

  float* g     = (float*)d_ws;                     // 2048*256
  float* s_l   = g + N_NODES * OUTF;               // 2048*8
  float* s_r_t = s_l + N_NODES * NH;               // 8*2048
  float* pout  = s_r_t + NH * N_NODES;             // JSPLIT * 2048*256
  float* pl    = pout + JSPLIT * N_NODES * OUTF;   // JSPLIT * 2048*8

  gemm_g_kernel<<<dim3(N_NODES / TM, OUTF / TN), 256, 0, stream>>>(h, W, g);
  score_kernel<<<(N_NODES * NH) / 256, 256, 0, stream>>>(g, a, s_l, s_r_t);
  pv_partial_kernel<<<dim3(N_NODES / 8, JSPLIT), 512, 0, stream>>>(adj, g, s_l, s_r_t, pout, pl);
  reduce_kernel<<<(N_NODES * OUTF) / 256, 256, 0, stream>>>(pout, pl, out);
}

// Round 3
// 76.185 us; speedup vs baseline: 3.6258x; 2.4473x over previous
//
#include <hip/hip_runtime.h>
#include <hip/hip_bf16.h>
#include <math.h>

#define N_NODES 2048
#define IN_F    1024
#define NH      8
#define HF      32
#define OUTF    256   // NH*HF
#define JSPLIT  4
#define JR      (N_NODES / JSPLIT)   // 512 j's per attention block

typedef __attribute__((ext_vector_type(8))) short short8;
typedef __attribute__((ext_vector_type(4))) float f32x4;

__device__ __forceinline__ short f2bf(float x) {   // fp32 -> bf16 bits, RNE
  unsigned u = __float_as_uint(x);
  return (short)((u + 0x7FFFu + ((u >> 16) & 1u)) >> 16);
}
__device__ __forceinline__ float bf2f(short b) {
  return __uint_as_float(((unsigned)(unsigned short)b) << 16);
}

// ---------------- Kernel 1: partial g = h @ W, K-split 4 -------------------
#define TM 64
#define TN 32
#define TK 32
#define KSPLIT 4

__global__ __launch_bounds__(256)
void gemm_part_kernel(const float* __restrict__ A, const float* __restrict__ B,
                      float* __restrict__ gp) {
  __shared__ float As[TK][TM + 1];
  __shared__ float Bs[TK][TN + 1];
  const int m0 = blockIdx.x * TM;
  const int c0 = blockIdx.y * TN;
  const int kb = blockIdx.z * (IN_F / KSPLIT);
  const int tid = threadIdx.x;
  const int tx = tid & 15;
  const int ty = tid >> 4;
  float acc[4][2] = {{0.f,0.f},{0.f,0.f},{0.f,0.f},{0.f,0.f}};

  for (int k0 = kb; k0 < kb + IN_F / KSPLIT; k0 += TK) {
    {
      const int kk = tid & 31, m = tid >> 5;
      #pragma unroll
      for (int r = 0; r < 8; ++r)
        As[kk][m + r * 8] = A[(m0 + m + r * 8) * IN_F + k0 + kk];
    }
    {
      const int c = tid & 31, kk = tid >> 5;
      #pragma unroll
      for (int r = 0; r < 4; ++r)
        Bs[kk + r * 8][c] = B[(k0 + kk + r * 8) * OUTF + c0 + c];
    }
    __syncthreads();
    #pragma unroll
    for (int kk = 0; kk < TK; ++kk) {
      const float a0 = As[kk][ty * 4 + 0];
      const float a1 = As[kk][ty * 4 + 1];
      const float a2 = As[kk][ty * 4 + 2];
      const float a3 = As[kk][ty * 4 + 3];
      const float b0 = Bs[kk][tx * 2 + 0];
      const float b1 = Bs[kk][tx * 2 + 1];
      acc[0][0] = fmaf(a0, b0, acc[0][0]); acc[0][1] = fmaf(a0, b1, acc[0][1]);
      acc[1][0] = fmaf(a1, b0, acc[1][0]); acc[1][1] = fmaf(a1, b1, acc[1][1]);
      acc[2][0] = fmaf(a2, b0, acc[2][0]); acc[2][1] = fmaf(a2, b1, acc[2][1]);
      acc[3][0] = fmaf(a3, b0, acc[3][0]); acc[3][1] = fmaf(a3, b1, acc[3][1]);
    }
    __syncthreads();
  }
  float* op = gp + blockIdx.z * (N_NODES * OUTF);
  #pragma unroll
  for (int r = 0; r < 4; ++r) {
    const int row = m0 + ty * 4 + r;
    #pragma unroll
    for (int c = 0; c < 2; ++c)
      op[row * OUTF + c0 + tx * 2 + c] = acc[r][c];
  }
}

// ---------------- Kernel 2: pack adj into bitmask [2048][64] u32 -----------
__global__ __launch_bounds__(256)
void pack_bits_kernel(const int* __restrict__ adj, unsigned* __restrict__ bits) {
  const int idx = blockIdx.x * 256 + threadIdx.x;   // row*64 + word
  const int4* p = (const int4*)(adj + (idx >> 6) * N_NODES + (idx & 63) * 32);
  unsigned w = 0;
  #pragma unroll
  for (int v = 0; v < 8; ++v) {
    const int4 x = p[v];
    w |= (x.x != 0 ? 1u : 0u) << (4 * v + 0);
    w |= (x.y != 0 ? 1u : 0u) << (4 * v + 1);
    w |= (x.z != 0 ? 1u : 0u) << (4 * v + 2);
    w |= (x.w != 0 ? 1u : 0u) << (4 * v + 3);
  }
  bits[idx] = w;
}

// ---------------- Kernel 3: sum K-partials -> s_l, s_r_t, gt(bf16,T) -------
// block: 64 i-rows x 1 head. gt layout: [h][f][node] bf16 (j-contiguous).
__global__ __launch_bounds__(256)
void finish_g_kernel(const float* __restrict__ gp, const float* __restrict__ a,
                     short* __restrict__ gt, float* __restrict__ s_l,
                     float* __restrict__ s_r_t) {
  __shared__ float tile[64][36];   // stride 36: float4-aligned rows
  const int i0 = blockIdx.x * 64;
  const int h  = blockIdx.y;
  const int t  = threadIdx.x;
  {
    const int i = t & 63, fg = t >> 6;   // fg*8 .. fg*8+7
    const int base = (i0 + i) * OUTF + h * HF + fg * 8;
    float4 v0 = *(const float4*)(gp + base);
    float4 v1 = *(const float4*)(gp + base + 4);
    #pragma unroll
    for (int s = 1; s < KSPLIT; ++s) {
      const float4 u0 = *(const float4*)(gp + s * (N_NODES * OUTF) + base);
      const float4 u1 = *(const float4*)(gp + s * (N_NODES * OUTF) + base + 4);
      v0.x += u0.x; v0.y += u0.y; v0.z += u0.z; v0.w += u0.w;
      v1.x += u1.x; v1.y += u1.y; v1.z += u1.z; v1.w += u1.w;
    }
    *(float4*)&tile[i][fg * 8] = v0;
    *(float4*)&tile[i][fg * 8 + 4] = v1;
  }
  __syncthreads();
  if (t < 64) {
    float sl = 0.f, sr = 0.f;
    #pragma unroll
    for (int f = 0; f < HF; ++f) {
      const float gv = tile[t][f];
      sl = fmaf(gv, a[f], sl);
      sr = fmaf(gv, a[HF + f], sr);
    }
    s_l[(i0 + t) * NH + h] = sl;
    s_r_t[h * N_NODES + i0 + t] = sr;
  }
  {
    const int f = t & 31, ig = t >> 5;   // ig = 0..7
    short8 o;
    #pragma unroll
    for (int rr = 0; rr < 8; ++rr) o[rr] = f2bf(tile[8 * ig + rr][f]);
    *(short8*)(gt + (h * HF + f) * N_NODES + i0 + 8 * ig) = o;
  }
}

// ---------------- Kernel 4: MFMA attention partials (no LDS, no barriers) --
// grid (128 i-tiles, JSPLIT). 8 waves/block, wave = head. 16 i x 32 f per wave.
__global__ __launch_bounds__(512)
void attn_mfma_kernel(const unsigned* __restrict__ bits, const short* __restrict__ gt,
                      const float* __restrict__ s_l, const float* __restrict__ s_r_t,
                      float* __restrict__ pout, float* __restrict__ pl) {
  const int i0    = blockIdx.x * 16;
  const int split = blockIdx.y;
  const int tid   = threadIdx.x;
  const int h = tid >> 6;
  const int l = tid & 63;
  const int il = l & 15;        // A row / D col
  const int q  = l >> 4;        // k-group: k = 8q + r

  const float slv = s_l[(i0 + il) * NH + h];
  const unsigned* bitrow = bits + (i0 + il) * 64;
  const float* srh = s_r_t + h * N_NODES;
  const short* g0p = gt + (h * HF + il) * N_NODES;
  const short* g1p = gt + (h * HF + 16 + il) * N_NODES;

  f32x4 acc0 = {0.f, 0.f, 0.f, 0.f};
  f32x4 acc1 = {0.f, 0.f, 0.f, 0.f};
  float denom = 0.f;

  const int jbase = split * JR;
  for (int j0 = jbase; j0 < jbase + JR; j0 += 32) {
    const unsigned word = bitrow[j0 >> 5];
    const float4 sra = *(const float4*)(srh + j0 + 8 * q);
    const float4 srb = *(const float4*)(srh + j0 + 8 * q + 4);
    const float sr_[8] = {sra.x, sra.y, sra.z, sra.w, srb.x, srb.y, srb.z, srb.w};
    short8 afrag;
    #pragma unroll
    for (int r = 0; r < 8; ++r) {
      float e = slv + sr_[r];
      e = fmaxf(e, 0.2f * e);                                 // leaky relu
      const float wv = ((word >> (8 * q + r)) & 1u) ? __expf(e) : 0.f;
      const short wb = f2bf(wv);
      afrag[r] = wb;
      denom += bf2f(wb);    // denom consistent with bf16 numerator
    }
    const short8 b0 = *(const short8*)(g0p + j0 + 8 * q);
    const short8 b1 = *(const short8*)(g1p + j0 + 8 * q);
    acc0 = __builtin_amdgcn_mfma_f32_16x16x32_bf16(afrag, b0, acc0, 0, 0, 0);
    acc1 = __builtin_amdgcn_mfma_f32_16x16x32_bf16(afrag, b1, acc1, 0, 0, 0);
  }

  denom += __shfl_xor(denom, 16, 64);
  denom += __shfl_xor(denom, 32, 64);

  float* pb = pout + split * (N_NODES * OUTF);
  #pragma unroll
  for (int r = 0; r < 4; ++r) {
    const int irow = i0 + 4 * q + r;      // D: row = 4*(l>>4)+r, col = l&15
    pb[irow * OUTF + h * HF + il]      = acc0[r];
    pb[irow * OUTF + h * HF + 16 + il] = acc1[r];
  }
  if (q == 0) pl[split * (N_NODES * NH) + (i0 + il) * NH + h] = denom;
}

// ---------------- Kernel 5: sum partials, normalize ------------------------
__global__ __launch_bounds__(256)
void reduce_kernel(const float* __restrict__ pout, const float* __restrict__ pl,
                   float* __restrict__ out) {
  const int idx = blockIdx.x * 256 + threadIdx.x;  // over N_NODES*OUTF
  float s = 0.f;
  #pragma unroll
  for (int p = 0; p < JSPLIT; ++p) s += pout[p * (N_NODES * OUTF) + idx];
  const int ih = idx >> 5;  // i*8 + h
  float lsum = 0.f;
  #pragma unroll
  for (int p = 0; p < JSPLIT; ++p) lsum += pl[p * (N_NODES * NH) + ih];
  out[idx] = s / lsum;
}

// ---------------------------------------------------------------------------
extern "C" void kernel_launch(void* const* d_in, const int* in_sizes, int n_in,
                              void* d_out, int out_size, void* d_ws, size_t ws_size,
                              hipStream_t stream) {
  const float* h   = (const float*)d_in[0];
  const int*   adj = (const int*)d_in[1];
  const float* W   = (const float*)d_in[2];
  const float* a   = (const float*)d_in[3];
  float* out = (float*)d_out;

  float* gp    = (float*)d_ws;                       // 4 * 2048*256 (aliased w/ pout)
  float* pout  = gp;                                 // attn partials reuse gp
  float* s_l   = gp + KSPLIT * N_NODES * OUTF;       // 2048*8
  float* s_r_t = s_l + N_NODES * NH;                 // 8*2048
  float* pl    = s_r_t + NH * N_NODES;               // JSPLIT * 2048*8
  unsigned* bits = (unsigned*)(pl + JSPLIT * N_NODES * NH);   // 2048*64 u32
  short* gt    = (short*)(bits + N_NODES * 64);      // 8*32*2048 bf16

  gemm_part_kernel<<<dim3(N_NODES / TM, OUTF / TN, KSPLIT), 256, 0, stream>>>(h, W, gp);
  pack_bits_kernel<<<(N_NODES * 64) / 256, 256, 0, stream>>>(adj, bits);
  finish_g_kernel<<<dim3(N_NODES / 64, NH), 256, 0, stream>>>(gp, a, gt, s_l, s_r_t);
  attn_mfma_kernel<<<dim3(N_NODES / 16, JSPLIT), 512, 0, stream>>>(bits, gt, s_l, s_r_t, pout, pl);
  reduce_kernel<<<(N_NODES * OUTF) / 256, 256, 0, stream>>>(pout, pl, out);
}